// Round 11
// baseline (178.726 us; speedup 1.0000x reference)
//
#include <hip/hip_runtime.h>

#define D_MODEL 1024
#define HEADS   16
#define DK      64
#define BATCH   2
#define TSEQ    2048
#define NTOK    (BATCH * TSEQ)   // 4096

typedef __attribute__((ext_vector_type(8))) short bf16x8;
typedef __attribute__((ext_vector_type(4))) short s16x4;
typedef __attribute__((ext_vector_type(4))) float f32x4;
typedef __attribute__((ext_vector_type(2))) unsigned u32x2;
typedef __attribute__((ext_vector_type(4))) unsigned u32x4;

__device__ __forceinline__ short f2bf(float f) {
    union { float f; unsigned u; } a;
    a.f = f;
    unsigned r = a.u + 0x7FFFu + ((a.u >> 16) & 1u);
    return (short)(r >> 16);
}
// one-instruction packed f32->bf16x2 (RNE): lo = bf16(a), hi = bf16(b)
__device__ __forceinline__ unsigned cvt_pk_bf16(float a, float b) {
    unsigned r;
    asm("v_cvt_pk_bf16_f32 %0, %1, %2" : "=v"(r) : "v"(a), "v"(b));
    return r;
}

// async global->LDS, 16B per lane. LDS dest = wave-uniform base + lane*16.
__device__ __forceinline__ void gl_lds16(const void* g, void* l) {
    __builtin_amdgcn_global_load_lds(
        (const __attribute__((address_space(1))) unsigned int*)(unsigned long long)g,
        (__attribute__((address_space(3))) unsigned int*)(unsigned int)(unsigned long long)l,
        16, 0, 0);
}

// P-fragment redistribution: permlane32_swap + permlane16_swap pair.
__device__ __forceinline__ void pl_swap(unsigned& a, unsigned& b) {
    u32x2 r32 = __builtin_amdgcn_permlane32_swap(a, b, false, false);
    u32x2 r16 = __builtin_amdgcn_permlane16_swap(r32[0], r32[1], false, false);
    a = r16[0]; b = r16[1];
}

// ------------------------------------------------- fused prep: transposes + cvt
// Scalar r5 version (in the 168.6 best; r8's vectorized rewrite was +24 us,
// confirmed by r5/r8/r10 budget algebra).
__global__ __launch_bounds__(256) void prep_kernel(
    const float* __restrict__ x, const float* __restrict__ Wqkv,
    const float* __restrict__ Wout,
    short* __restrict__ xb, short* __restrict__ wqkvt, short* __restrict__ woutt)
{
    int bx = blockIdx.x;
    if (bx < 4096) {
        __shared__ float tile[32][33];
        const float* in; short* out; int N, n0, k0;
        if (bx < 3072) { in = Wqkv; out = wqkvt; N = 3072; n0 = (bx % 96) * 32; k0 = (bx / 96) * 32; }
        else { int t2 = bx - 3072; in = Wout; out = woutt; N = 1024; n0 = (t2 & 31) * 32; k0 = (t2 >> 5) * 32; }
        int tx = threadIdx.x & 31, ty = threadIdx.x >> 5;
        #pragma unroll
        for (int i = 0; i < 32; i += 8)
            tile[ty + i][tx] = in[(long)(k0 + ty + i) * N + n0 + tx];
        __syncthreads();
        #pragma unroll
        for (int i = 0; i < 32; i += 8)
            out[(long)(n0 + ty + i) * 1024 + k0 + tx] = f2bf(tile[tx][ty + i]);
    } else {
        long i = ((long)(bx - 4096) * 256 + threadIdx.x) * 4;
        float4 v = *(const float4*)&x[i];
        s16x4 o;
        o[0] = f2bf(v.x); o[1] = f2bf(v.y); o[2] = f2bf(v.z); o[3] = f2bf(v.w);
        *(s16x4*)&xb[i] = o;
    }
}

// ---------------------------------------------------------------- QKV GEMM
// m97-class single-buffer 128x128, no XCD swizzle (r8: <=50.3, r10: 61.2 —
// cross-round variance band; source unchanged).
__global__ __launch_bounds__(256) void gemm_qkv_kernel(
    const short* __restrict__ A, const short* __restrict__ Bt,
    const float* __restrict__ bias,
    short* __restrict__ qo, short* __restrict__ ko, short* __restrict__ vt)
{
    const int K = 1024;
    __shared__ short As[128 * 64];   // [row*64 + (chunk^(row&7))*8]
    __shared__ short Bs[128 * 64];

    int tid  = threadIdx.x;
    int wid  = tid >> 6, lane = tid & 63;
    int wm   = wid >> 1, wn   = wid & 1;
    int g    = lane >> 4, l15 = lane & 15;
    int swzr = l15 & 7;
    long m0  = (long)blockIdx.x * 128;
    long n0  = (long)blockIdx.y * 128;

    f32x4 acc[4][4];
    #pragma unroll
    for (int i = 0; i < 4; i++)
        #pragma unroll
        for (int j = 0; j < 4; j++)
            acc[i][j] = (f32x4){0.f, 0.f, 0.f, 0.f};

    int srow = wid * 32 + (lane >> 3);
    int sch  = ((lane & 7) ^ ((lane >> 3) & 7)) * 8;   // shorts
    const short* Abase = A  + (m0 + srow) * K + sch;
    const short* Bbase = Bt + (n0 + srow) * K + sch;
    short* adst = &As[wid * 32 * 64];
    short* bdst = &Bs[wid * 32 * 64];

    for (int k0 = 0; k0 < K; k0 += 64) {
        #pragma unroll
        for (int s = 0; s < 4; s++) {
            gl_lds16(Abase + (long)s * 8 * K + k0, adst + s * 8 * 64);
            gl_lds16(Bbase + (long)s * 8 * K + k0, bdst + s * 8 * 64);
        }
        __syncthreads();

        bf16x8 af[4][2], bfr[4][2];
        #pragma unroll
        for (int i = 0; i < 4; i++)
            #pragma unroll
            for (int c = 0; c < 2; c++)
                af[i][c] = *(const bf16x8*)&As[(wm * 64 + i * 16 + l15) * 64 + (((c * 4 + g) ^ swzr) << 3)];
        #pragma unroll
        for (int j = 0; j < 4; j++)
            #pragma unroll
            for (int c = 0; c < 2; c++)
                bfr[j][c] = *(const bf16x8*)&Bs[(wn * 64 + j * 16 + l15) * 64 + (((c * 4 + g) ^ swzr) << 3)];

        #pragma unroll
        for (int c = 0; c < 2; c++)
            #pragma unroll
            for (int i = 0; i < 4; i++)
                #pragma unroll
                for (int j = 0; j < 4; j++)
                    acc[i][j] = __builtin_amdgcn_mfma_f32_16x16x32_bf16(af[i][c], bfr[j][c], acc[i][j], 0, 0, 0);

        __syncthreads();
    }

    // epilogue: D[m = (lane>>4)*4 + reg][n = lane&15]
    #pragma unroll
    for (int j = 0; j < 4; j++) {
        int n = (int)n0 + wn * 64 + j * 16 + l15;
        float bb = bias[n];
        #pragma unroll
        for (int i = 0; i < 4; i++) {
            int mrow = (int)m0 + wm * 64 + i * 16 + g * 4;
            if (n < 1024) {
                const float QS = 0.125f * 1.44269504088896f;   // log2e/sqrt(dk)
                #pragma unroll
                for (int r = 0; r < 4; r++)
                    qo[(long)(mrow + r) * 1024 + n] = f2bf((acc[i][j][r] + bb) * QS);
            } else if (n < 2048) {
                #pragma unroll
                for (int r = 0; r < 4; r++)
                    ko[(long)(mrow + r) * 1024 + (n - 1024)] = f2bf(acc[i][j][r] + bb);
            } else {
                int c = n - 2048, h = c >> 6, d = c & 63;
                int b = mrow >> 11, t = mrow & 2047;
                s16x4 pk;
                #pragma unroll
                for (int r = 0; r < 4; r++) pk[r] = f2bf(acc[i][j][r] + bb);
                *(s16x4*)&vt[((long)((b * 16 + h) * 64 + d)) * 2048 + t] = pk;
            }
        }
    }
}

// ---------------------------------------------------------------- out-proj GEMM
// dbuf 128x64 (r5/r8/r10): STAGE-early single-barrier, 48KB LDS, grid 32x16.
__global__ __launch_bounds__(256, 2) void gemm_out_kernel(
    const short* __restrict__ A, const short* __restrict__ Bt,
    const float* __restrict__ bias, float* __restrict__ fout)
{
    const int K = 1024;
    constexpr int BM = 128, BN = 64;
    constexpr int MI = 4, NJ = 2;
    constexpr int RA = 32, RB = 16;
    constexpr int SA = 4, SB = 2;

    __shared__ short smem[2 * (BM + BN) * 64];

    int tid  = threadIdx.x;
    int wid  = tid >> 6, lane = tid & 63;
    int wm   = wid >> 1, wn = wid & 1;
    int g    = lane >> 4, l15 = lane & 15;
    int swzr = l15 & 7;
    long m0  = (long)blockIdx.x * BM;
    long n0  = (long)blockIdx.y * BN;

    f32x4 acc[MI][NJ];
    #pragma unroll
    for (int i = 0; i < MI; i++)
        #pragma unroll
        for (int j = 0; j < NJ; j++)
            acc[i][j] = (f32x4){0.f, 0.f, 0.f, 0.f};

    int srow = lane >> 3;
    int sch  = ((lane & 7) ^ ((lane >> 3) & 7)) * 8;
    const short* Abase = A  + (m0 + wid * RA + srow) * K + sch;
    const short* Bbase = Bt + (n0 + wid * RB + srow) * K + sch;
    short* adst = smem + (wid * RA) * 64;
    short* bdst = smem + 2 * BM * 64 + (wid * RB) * 64;

    #pragma unroll
    for (int s = 0; s < SA; s++) gl_lds16(Abase + (long)s * 8 * K, adst + s * 8 * 64);
    #pragma unroll
    for (int s = 0; s < SB; s++) gl_lds16(Bbase + (long)s * 8 * K, bdst + s * 8 * 64);
    __syncthreads();

    for (int k0 = 0; k0 < K; k0 += 64) {
        int cur = (k0 >> 6) & 1, nxt = cur ^ 1;
        if (k0 + 64 < K) {
            #pragma unroll
            for (int s = 0; s < SA; s++)
                gl_lds16(Abase + (long)s * 8 * K + k0 + 64, adst + nxt * BM * 64 + s * 8 * 64);
            #pragma unroll
            for (int s = 0; s < SB; s++)
                gl_lds16(Bbase + (long)s * 8 * K + k0 + 64, bdst + nxt * BN * 64 + s * 8 * 64);
        }
        const short* Asb = smem + cur * BM * 64;
        const short* Bsb = smem + 2 * BM * 64 + cur * BN * 64;

        #pragma unroll
        for (int c = 0; c < 2; c++) {
            bf16x8 bfr[NJ];
            #pragma unroll
            for (int j = 0; j < NJ; j++)
                bfr[j] = *(const bf16x8*)&Bsb[(wn * 32 + j * 16 + l15) * 64 + (((c * 4 + g) ^ swzr) << 3)];
            bf16x8 af[MI];
            #pragma unroll
            for (int i = 0; i < MI; i++)
                af[i] = *(const bf16x8*)&Asb[(wm * 64 + i * 16 + l15) * 64 + (((c * 4 + g) ^ swzr) << 3)];
            #pragma unroll
            for (int i = 0; i < MI; i++)
                #pragma unroll
                for (int j = 0; j < NJ; j++)
                    acc[i][j] = __builtin_amdgcn_mfma_f32_16x16x32_bf16(af[i], bfr[j], acc[i][j], 0, 0, 0);
        }
        __syncthreads();
    }

    #pragma unroll
    for (int j = 0; j < NJ; j++) {
        int n = (int)n0 + wn * 32 + j * 16 + l15;
        float bb = bias[n];
        #pragma unroll
        for (int i = 0; i < MI; i++) {
            int mrow = (int)m0 + wm * 64 + i * 16 + g * 4;
            #pragma unroll
            for (int r = 0; r < 4; r++)
                fout[(long)(mrow + r) * 1024 + n] = acc[i][j][r] + bb;
        }
    }
}

// ---------------------------------------------------------------- flash attention
// r7/r8 EXACT version (50.4/50.3 us twice): per-read XOR addressing — the
// expressions are loop-invariant and the compiler hoists all 16 LDS addresses
// once; r9's "derived-base" rewrite defeated that hoist and cost ~10 us
// (r10 budget algebra). Q-tile-128, cvt_pk pack, XCD head-cluster swizzle,
// setprio around MFMA clusters.
__global__ __launch_bounds__(256) void flash_attn_kernel(
    const short* __restrict__ qb, const short* __restrict__ kb,
    const short* __restrict__ vt, short* __restrict__ ob)
{
    __shared__ short Ks[2][64 * 64];          // [buf][key*64 + swz(chunk)*8]
    __shared__ short Vs[2][64 * 64];          // [buf][d*64 + swz(chunk)*8]

    int tid = threadIdx.x, wid = tid >> 6, lane = tid & 63;
    int g = lane >> 4, l15 = lane & 15;
    int swzr = l15 & 7;

    // XCD swizzle: 512 blocks on 8 XCDs; XCD k owns heads [4k,4k+4).
    int fid = blockIdx.y * 16 + blockIdx.x;    // gridDim.x = 16
    int swb = (fid & 7) * 64 + (fid >> 3);
    int bh  = swb >> 4;
    int qt  = swb & 15;
    int b = bh >> 4, h = bh & 15;
    int q0w = qt * 128 + wid * 32;
    long qrow = (long)b * TSEQ + q0w;

    bf16x8 qf[2][2];
    #pragma unroll
    for (int qg = 0; qg < 2; qg++)
        #pragma unroll
        for (int c = 0; c < 2; c++)
            qf[qg][c] = *(const bf16x8*)&qb[(qrow + qg * 16 + l15) * 1024 + h * 64 + c * 32 + g * 8];

    bf16x8 ones;
    #pragma unroll
    for (int j = 0; j < 8; j++) ones[j] = (short)0x3F80;   // bf16 1.0

    f32x4 oacc[2][4], lacc[2];
    #pragma unroll
    for (int qg = 0; qg < 2; qg++) {
        lacc[qg] = (f32x4){0.f, 0.f, 0.f, 0.f};
        #pragma unroll
        for (int jt = 0; jt < 4; jt++) oacc[qg][jt] = (f32x4){0.f, 0.f, 0.f, 0.f};
    }

    const short* kg = kb + ((long)b * TSEQ) * 1024 + h * 64;   // + key*1024 + d
    const short* vg = vt + ((long)bh * 64) * 2048;             // + d*2048 + key

    int ch = (((lane & 7) ^ ((lane >> 3) & 7))) * 8;
    int r0 = wid * 16 + (lane >> 3);
    int r1 = r0 + 8;
    short* kdst0 = &Ks[0][(wid * 2 + 0) * 512];
    short* kdst1 = &Ks[0][(wid * 2 + 1) * 512];
    short* vdst0 = &Vs[0][(wid * 2 + 0) * 512];
    short* vdst1 = &Vs[0][(wid * 2 + 1) * 512];

    #define STAGE(buf, kt)                                                        \
        gl_lds16(kg + (long)((kt) * 64 + r0) * 1024 + ch, kdst0 + (buf) * 4096);  \
        gl_lds16(kg + (long)((kt) * 64 + r1) * 1024 + ch, kdst1 + (buf) * 4096);  \
        gl_lds16(vg + (long)r0 * 2048 + (kt) * 64 + ch,   vdst0 + (buf) * 4096);  \
        gl_lds16(vg + (long)r1 * 2048 + (kt) * 64 + ch,   vdst1 + (buf) * 4096);

    #define BODY(cur, nxt, kt, do_pref)                                                  \
    {                                                                                    \
        if (do_pref) { STAGE(nxt, (kt) + 1) }                                            \
        bf16x8 kf[4][2], vf[4][2];                                                       \
        _Pragma("unroll")                                                                \
        for (int jt = 0; jt < 4; jt++)                                                   \
            _Pragma("unroll")                                                            \
            for (int c = 0; c < 2; c++) {                                                \
                int off = (jt * 16 + l15) * 64 + (((c * 4 + g) ^ swzr) << 3);            \
                kf[jt][c] = *(const bf16x8*)&Ks[cur][off];                               \
                vf[jt][c] = *(const bf16x8*)&Vs[cur][off];                               \
            }                                                                            \
        _Pragma("unroll")                                                                \
        for (int qg = 0; qg < 2; qg++) {                                                 \
            f32x4 s[4];                                                                  \
            __builtin_amdgcn_s_setprio(1);                                               \
            _Pragma("unroll")                                                            \
            for (int jt = 0; jt < 4; jt++) {                                             \
                f32x4 t = (f32x4){0.f, 0.f, 0.f, 0.f};                                   \
                t = __builtin_amdgcn_mfma_f32_16x16x32_bf16(kf[jt][0], qf[qg][0], t, 0, 0, 0); \
                t = __builtin_amdgcn_mfma_f32_16x16x32_bf16(kf[jt][1], qf[qg][1], t, 0, 0, 0); \
                s[jt] = t;                                                               \
            }                                                                            \
            __builtin_amdgcn_s_setprio(0);                                               \
            unsigned up[4][2];                                                           \
            _Pragma("unroll")                                                            \
            for (int jt = 0; jt < 4; jt++) {                                             \
                float p0 = __builtin_amdgcn_exp2f(s[jt][0]);                             \
                float p1 = __builtin_amdgcn_exp2f(s[jt][1]);                             \
                float p2 = __builtin_amdgcn_exp2f(s[jt][2]);                             \
                float p3 = __builtin_amdgcn_exp2f(s[jt][3]);                             \
                up[jt][0] = cvt_pk_bf16(p0, p1);                                         \
                up[jt][1] = cvt_pk_bf16(p2, p3);                                         \
            }                                                                            \
            _Pragma("unroll")                                                            \
            for (int hh = 0; hh < 2; hh++) {                                             \
                pl_swap(up[0][hh], up[1][hh]);                                           \
                pl_swap(up[2][hh], up[3][hh]);                                           \
            }                                                                            \
            bf16x8 pA0 = __builtin_bit_cast(bf16x8, (u32x4){up[0][0], up[0][1], up[1][0], up[1][1]}); \
            bf16x8 pA1 = __builtin_bit_cast(bf16x8, (u32x4){up[2][0], up[2][1], up[3][0], up[3][1]}); \
            __builtin_amdgcn_s_setprio(1);                                               \
            lacc[qg] = __builtin_amdgcn_mfma_f32_16x16x32_bf16(pA0, ones, lacc[qg], 0, 0, 0); \
            lacc[qg] = __builtin_amdgcn_mfma_f32_16x16x32_bf16(pA1, ones, lacc[qg], 0, 0, 0); \
            _Pragma("unroll")                                                            \
            for (int jt = 0; jt < 4; jt++) {                                             \
                oacc[qg][jt] = __builtin_amdgcn_mfma_f32_16x16x32_bf16(pA0, vf[jt][0], oacc[qg][jt], 0, 0, 0); \
                oacc[qg][jt] = __builtin_amdgcn_mfma_f32_16x16x32_bf16(pA1, vf[jt][1], oacc[qg][jt], 0, 0, 0); \
            }                                                                            \
            __builtin_amdgcn_s_setprio(0);                                               \
        }                                                                                \
        __syncthreads();                                                                 \
    }

    STAGE(0, 0)
    __syncthreads();

    for (int kt = 0; kt < TSEQ / 64; kt += 2) {
        BODY(0, 1, kt, 1)
        BODY(1, 0, kt + 1, (kt + 2 < TSEQ / 64))
    }
    #undef BODY
    #undef STAGE

    // oacc/lacc C-layout: row = q_local = g*4+r, col = l15.
    #pragma unroll
    for (int qg = 0; qg < 2; qg++)
        #pragma unroll
        for (int r = 0; r < 4; r++) {
            float inv = 1.f / lacc[qg][r];
            long row = qrow + qg * 16 + g * 4 + r;
            #pragma unroll
            for (int jt = 0; jt < 4; jt++)
                ob[row * 1024 + h * 64 + jt * 16 + l15] = f2bf(oacc[qg][jt][r] * inv);
        }
}

// ---------------------------------------------------------------- launcher
extern "C" void kernel_launch(void* const* d_in, const int* in_sizes, int n_in,
                              void* d_out, int out_size, void* d_ws, size_t ws_size,
                              hipStream_t stream)
{
    const float* x    = (const float*)d_in[0];
    const float* Wqkv = (const float*)d_in[1];
    const float* bqkv = (const float*)d_in[2];
    const float* Wout = (const float*)d_in[3];
    const float* bout = (const float*)d_in[4];
    float* out = (float*)d_out;

    char* ws = (char*)d_ws;
    const size_t SZ_TOKD = (size_t)NTOK * 1024 * sizeof(short);   // 8 MB
    short* xb    = (short*)ws;                 ws += SZ_TOKD;
    short* wqkvt = (short*)ws;                 ws += (size_t)3072 * 1024 * sizeof(short);
    short* woutt = (short*)ws;                 ws += (size_t)1024 * 1024 * sizeof(short);
    short* qb    = (short*)ws;                 ws += SZ_TOKD;
    short* kb    = (short*)ws;                 ws += SZ_TOKD;
    short* vt    = (short*)ws;                 ws += SZ_TOKD;
    short* ob    = (short*)ws;                 ws += SZ_TOKD;
    if ((size_t)(ws - (char*)d_ws) > ws_size) return;   // workspace too small

    prep_kernel<<<8192, 256, 0, stream>>>(x, Wqkv, Wout, xb, wqkvt, woutt);

    gemm_qkv_kernel<<<dim3(NTOK / 128, 3072 / 128), 256, 0, stream>>>(
        xb, wqkvt, bqkv, qb, kb, vt);

    flash_attn_kernel<<<dim3(TSEQ / 128, BATCH * HEADS), 256, 0, stream>>>(qb, kb, vt, ob);

    gemm_out_kernel<<<dim3(NTOK / 128, 1024 / 64), 256, 0, stream>>>(
        ob, woutt, bout, out);
}

// Round 12
// 167.760 us; speedup vs baseline: 1.0654x; 1.0654x over previous
//
#include <hip/hip_runtime.h>

#define D_MODEL 1024
#define HEADS   16
#define DK      64
#define BATCH   2
#define TSEQ    2048
#define NTOK    (BATCH * TSEQ)   // 4096

typedef __attribute__((ext_vector_type(8))) short bf16x8;
typedef __attribute__((ext_vector_type(4))) short s16x4;
typedef __attribute__((ext_vector_type(4))) float f32x4;
typedef __attribute__((ext_vector_type(2))) unsigned u32x2;
typedef __attribute__((ext_vector_type(4))) unsigned u32x4;

__device__ __forceinline__ short f2bf(float f) {
    union { float f; unsigned u; } a;
    a.f = f;
    unsigned r = a.u + 0x7FFFu + ((a.u >> 16) & 1u);
    return (short)(r >> 16);
}
// one-instruction packed f32->bf16x2 (RNE): lo = bf16(a), hi = bf16(b)
__device__ __forceinline__ unsigned cvt_pk_bf16(float a, float b) {
    unsigned r;
    asm("v_cvt_pk_bf16_f32 %0, %1, %2" : "=v"(r) : "v"(a), "v"(b));
    return r;
}

// async global->LDS, 16B per lane. LDS dest = wave-uniform base + lane*16.
__device__ __forceinline__ void gl_lds16(const void* g, void* l) {
    __builtin_amdgcn_global_load_lds(
        (const __attribute__((address_space(1))) unsigned int*)(unsigned long long)g,
        (__attribute__((address_space(3))) unsigned int*)(unsigned int)(unsigned long long)l,
        16, 0, 0);
}

// P-fragment redistribution: permlane32_swap + permlane16_swap pair.
__device__ __forceinline__ void pl_swap(unsigned& a, unsigned& b) {
    u32x2 r32 = __builtin_amdgcn_permlane32_swap(a, b, false, false);
    u32x2 r16 = __builtin_amdgcn_permlane16_swap(r32[0], r32[1], false, false);
    a = r16[0]; b = r16[1];
}

// ------------------------------------------------- fused prep: transposes + cvt
__global__ __launch_bounds__(256) void prep_kernel(
    const float* __restrict__ x, const float* __restrict__ Wqkv,
    const float* __restrict__ Wout,
    short* __restrict__ xb, short* __restrict__ wqkvt, short* __restrict__ woutt)
{
    int bx = blockIdx.x;
    if (bx < 4096) {
        __shared__ float tile[32][33];
        const float* in; short* out; int N, n0, k0;
        if (bx < 3072) { in = Wqkv; out = wqkvt; N = 3072; n0 = (bx % 96) * 32; k0 = (bx / 96) * 32; }
        else { int t2 = bx - 3072; in = Wout; out = woutt; N = 1024; n0 = (t2 & 31) * 32; k0 = (t2 >> 5) * 32; }
        int tx = threadIdx.x & 31, ty = threadIdx.x >> 5;
        #pragma unroll
        for (int i = 0; i < 32; i += 8)
            tile[ty + i][tx] = in[(long)(k0 + ty + i) * N + n0 + tx];
        __syncthreads();
        #pragma unroll
        for (int i = 0; i < 32; i += 8)
            out[(long)(n0 + ty + i) * 1024 + k0 + tx] = f2bf(tile[tx][ty + i]);
    } else {
        long i = ((long)(bx - 4096) * 256 + threadIdx.x) * 4;
        float4 v = *(const float4*)&x[i];
        s16x4 o;
        o[0] = f2bf(v.x); o[1] = f2bf(v.y); o[2] = f2bf(v.z); o[3] = f2bf(v.w);
        *(s16x4*)&xb[i] = o;
    }
}

// ---------------------------------------------------------------- bf16 MFMA GEMM
// r5-exact template (the 168.6 build): big-tile dbuf STAGE-early single-barrier.
// MODE 0: 256x192 tile, 8 waves (wave-tile 128x48), grid 16x16 = 256.
// MODE 1: 128x64 tile, 4 waves (wave-tile 64x32), grid 32x16 = 512.
template<int MODE>
__global__ __launch_bounds__((MODE == 1) ? 256 : 512, 2) void gemm_bf16_kernel(
    const short* __restrict__ A, const short* __restrict__ Bt,
    const float* __restrict__ bias,
    short* __restrict__ qo, short* __restrict__ ko, short* __restrict__ vt,
    float* __restrict__ fout)
{
    const int K = 1024;
    constexpr int BM = (MODE == 1) ? 128 : 256;
    constexpr int BN = (MODE == 1) ? 64 : 192;
    constexpr int WM = 2;
    constexpr int WN = (MODE == 1) ? 2 : 4;
    constexpr int NW = WM * WN;                 // waves per block
    constexpr int MI = BM / WM / 16;            // m-subtiles per wave (4 / 8)
    constexpr int NJ = BN / WN / 16;            // n-subtiles per wave (2 / 3)
    constexpr int RA = BM / NW;                 // A rows staged per wave (32 / 32)
    constexpr int RB = BN / NW;                 // B rows staged per wave (16 / 24)
    constexpr int SA = RA / 8, SB = RB / 8;     // gl_lds16 sweeps

    __shared__ short smem[2 * (BM + BN) * 64];  // [A buf0|A buf1|B buf0|B buf1]

    int tid  = threadIdx.x;
    int wid  = tid >> 6, lane = tid & 63;
    int wm   = wid / WN, wn = wid % WN;
    int g    = lane >> 4, l15 = lane & 15;
    int swzr = l15 & 7;
    long m0  = (long)blockIdx.x * BM;
    long n0  = (long)blockIdx.y * BN;

    f32x4 acc[MI][NJ];
    #pragma unroll
    for (int i = 0; i < MI; i++)
        #pragma unroll
        for (int j = 0; j < NJ; j++)
            acc[i][j] = (f32x4){0.f, 0.f, 0.f, 0.f};

    int srow = lane >> 3;                               // row within 8-row strip
    int sch  = ((lane & 7) ^ ((lane >> 3) & 7)) * 8;    // pre-swizzled chunk (shorts)
    const short* Abase = A  + (m0 + wid * RA + srow) * K + sch;
    const short* Bbase = Bt + (n0 + wid * RB + srow) * K + sch;
    short* adst = smem + (wid * RA) * 64;               // + buf*BM*64
    short* bdst = smem + 2 * BM * 64 + (wid * RB) * 64; // + buf*BN*64

    // prologue: stage k-tile 0 into buf 0
    #pragma unroll
    for (int s = 0; s < SA; s++) gl_lds16(Abase + (long)s * 8 * K, adst + s * 8 * 64);
    #pragma unroll
    for (int s = 0; s < SB; s++) gl_lds16(Bbase + (long)s * 8 * K, bdst + s * 8 * 64);
    __syncthreads();

    for (int k0 = 0; k0 < K; k0 += 64) {
        int cur = (k0 >> 6) & 1, nxt = cur ^ 1;
        if (k0 + 64 < K) {   // prefetch next k-tile into the other buffer
            #pragma unroll
            for (int s = 0; s < SA; s++)
                gl_lds16(Abase + (long)s * 8 * K + k0 + 64, adst + nxt * BM * 64 + s * 8 * 64);
            #pragma unroll
            for (int s = 0; s < SB; s++)
                gl_lds16(Bbase + (long)s * 8 * K + k0 + 64, bdst + nxt * BN * 64 + s * 8 * 64);
        }
        const short* Asb = smem + cur * BM * 64;
        const short* Bsb = smem + 2 * BM * 64 + cur * BN * 64;

        #pragma unroll
        for (int c = 0; c < 2; c++) {
            bf16x8 bfr[NJ];
            #pragma unroll
            for (int j = 0; j < NJ; j++)
                bfr[j] = *(const bf16x8*)&Bsb[(wn * (BN / WN) + j * 16 + l15) * 64 + (((c * 4 + g) ^ swzr) << 3)];
            bf16x8 af[MI];
            #pragma unroll
            for (int i = 0; i < MI; i++)
                af[i] = *(const bf16x8*)&Asb[(wm * (BM / WM) + i * 16 + l15) * 64 + (((c * 4 + g) ^ swzr) << 3)];
            #pragma unroll
            for (int i = 0; i < MI; i++)
                #pragma unroll
                for (int j = 0; j < NJ; j++)
                    acc[i][j] = __builtin_amdgcn_mfma_f32_16x16x32_bf16(af[i], bfr[j], acc[i][j], 0, 0, 0);
        }
        __syncthreads();   // publishes prefetch (vmcnt0) + guards cur-buf reuse
    }

    // epilogue: D[m = (lane>>4)*4 + reg][n = lane&15]
    #pragma unroll
    for (int j = 0; j < NJ; j++) {
        int n = (int)n0 + wn * (BN / WN) + j * 16 + l15;
        float bb = bias[n];
        #pragma unroll
        for (int i = 0; i < MI; i++) {
            int mrow = (int)m0 + wm * (BM / WM) + i * 16 + g * 4;
            if (MODE == 1) {
                #pragma unroll
                for (int r = 0; r < 4; r++)
                    fout[(long)(mrow + r) * 1024 + n] = acc[i][j][r] + bb;
            } else {
                if (n < 1024) {
                    const float QS = 0.125f * 1.44269504088896f;   // log2e/sqrt(dk)
                    #pragma unroll
                    for (int r = 0; r < 4; r++)
                        qo[(long)(mrow + r) * 1024 + n] = f2bf((acc[i][j][r] + bb) * QS);
                } else if (n < 2048) {
                    #pragma unroll
                    for (int r = 0; r < 4; r++)
                        ko[(long)(mrow + r) * 1024 + (n - 1024)] = f2bf(acc[i][j][r] + bb);
                } else {
                    int c = n - 2048, h = c >> 6, d = c & 63;
                    int b = mrow >> 11, t = mrow & 2047;
                    s16x4 pk;
                    #pragma unroll
                    for (int r = 0; r < 4; r++) pk[r] = f2bf(acc[i][j][r] + bb);
                    *(s16x4*)&vt[((long)((b * 16 + h) * 64 + d)) * 2048 + t] = pk;
                }
            }
        }
    }
}

// ---------------------------------------------------------------- flash attention
// grid: (TSEQ/128, BATCH*HEADS) = 512 blocks, block = 4 waves x 32 queries (2 qg).
// r5-exact: Q-tile-128, cvt_pk pack, XCD head-cluster swizzle, setprio.
__global__ __launch_bounds__(256) void flash_attn_kernel(
    const short* __restrict__ qb, const short* __restrict__ kb,
    const short* __restrict__ vt, short* __restrict__ ob)
{
    __shared__ short Ks[2][64 * 64];          // [buf][key*64 + swz(chunk)*8]
    __shared__ short Vs[2][64 * 64];          // [buf][d*64 + swz(chunk)*8]

    int tid = threadIdx.x, wid = tid >> 6, lane = tid & 63;
    int g = lane >> 4, l15 = lane & 15;
    int swzr = l15 & 7;

    // XCD swizzle: 512 blocks on 8 XCDs; XCD k owns heads [4k,4k+4) (2 MB K/V per
    // XCD L2). Bijective: fid = (fid&7)*64 + fid>>3, 512 % 8 == 0.
    int fid = blockIdx.y * 16 + blockIdx.x;    // gridDim.x = 16
    int swb = (fid & 7) * 64 + (fid >> 3);
    int bh  = swb >> 4;                        // 0..31
    int qt  = swb & 15;                        // q-tile 0..15
    int b = bh >> 4, h = bh & 15;
    int q0w = qt * 128 + wid * 32;
    long qrow = (long)b * TSEQ + q0w;

    bf16x8 qf[2][2];
    #pragma unroll
    for (int qg = 0; qg < 2; qg++)
        #pragma unroll
        for (int c = 0; c < 2; c++)
            qf[qg][c] = *(const bf16x8*)&qb[(qrow + qg * 16 + l15) * 1024 + h * 64 + c * 32 + g * 8];

    bf16x8 ones;
    #pragma unroll
    for (int j = 0; j < 8; j++) ones[j] = (short)0x3F80;   // bf16 1.0

    f32x4 oacc[2][4], lacc[2];
    #pragma unroll
    for (int qg = 0; qg < 2; qg++) {
        lacc[qg] = (f32x4){0.f, 0.f, 0.f, 0.f};
        #pragma unroll
        for (int jt = 0; jt < 4; jt++) oacc[qg][jt] = (f32x4){0.f, 0.f, 0.f, 0.f};
    }

    const short* kg = kb + ((long)b * TSEQ) * 1024 + h * 64;   // + key*1024 + d
    const short* vg = vt + ((long)bh * 64) * 2048;             // + d*2048 + key

    int ch = (((lane & 7) ^ ((lane >> 3) & 7))) * 8;   // swizzled global chunk offset
    int r0 = wid * 16 + (lane >> 3);
    int r1 = r0 + 8;
    short* kdst0 = &Ks[0][(wid * 2 + 0) * 512];
    short* kdst1 = &Ks[0][(wid * 2 + 1) * 512];
    short* vdst0 = &Vs[0][(wid * 2 + 0) * 512];
    short* vdst1 = &Vs[0][(wid * 2 + 1) * 512];

    #define STAGE(buf, kt)                                                        \
        gl_lds16(kg + (long)((kt) * 64 + r0) * 1024 + ch, kdst0 + (buf) * 4096);  \
        gl_lds16(kg + (long)((kt) * 64 + r1) * 1024 + ch, kdst1 + (buf) * 4096);  \
        gl_lds16(vg + (long)r0 * 2048 + (kt) * 64 + ch,   vdst0 + (buf) * 4096);  \
        gl_lds16(vg + (long)r1 * 2048 + (kt) * 64 + ch,   vdst1 + (buf) * 4096);

    #define BODY(cur, nxt, kt, do_pref)                                                  \
    {                                                                                    \
        if (do_pref) { STAGE(nxt, (kt) + 1) }                                            \
        bf16x8 kf[4][2], vf[4][2];                                                       \
        _Pragma("unroll")                                                                \
        for (int jt = 0; jt < 4; jt++)                                                   \
            _Pragma("unroll")                                                            \
            for (int c = 0; c < 2; c++) {                                                \
                int off = (jt * 16 + l15) * 64 + (((c * 4 + g) ^ swzr) << 3);            \
                kf[jt][c] = *(const bf16x8*)&Ks[cur][off];                               \
                vf[jt][c] = *(const bf16x8*)&Vs[cur][off];                               \
            }                                                                            \
        _Pragma("unroll")                                                                \
        for (int qg = 0; qg < 2; qg++) {                                                 \
            f32x4 s[4];                                                                  \
            __builtin_amdgcn_s_setprio(1);                                               \
            _Pragma("unroll")                                                            \
            for (int jt = 0; jt < 4; jt++) {                                             \
                f32x4 t = (f32x4){0.f, 0.f, 0.f, 0.f};                                   \
                t = __builtin_amdgcn_mfma_f32_16x16x32_bf16(kf[jt][0], qf[qg][0], t, 0, 0, 0); \
                t = __builtin_amdgcn_mfma_f32_16x16x32_bf16(kf[jt][1], qf[qg][1], t, 0, 0, 0); \
                s[jt] = t;                                                               \
            }                                                                            \
            __builtin_amdgcn_s_setprio(0);                                               \
            unsigned up[4][2];                                                           \
            _Pragma("unroll")                                                            \
            for (int jt = 0; jt < 4; jt++) {                                             \
                float p0 = __builtin_amdgcn_exp2f(s[jt][0]);                             \
                float p1 = __builtin_amdgcn_exp2f(s[jt][1]);                             \
                float p2 = __builtin_amdgcn_exp2f(s[jt][2]);                             \
                float p3 = __builtin_amdgcn_exp2f(s[jt][3]);                             \
                up[jt][0] = cvt_pk_bf16(p0, p1);                                         \
                up[jt][1] = cvt_pk_bf16(p2, p3);                                         \
            }                                                                            \
            _Pragma("unroll")                                                            \
            for (int hh = 0; hh < 2; hh++) {                                             \
                pl_swap(up[0][hh], up[1][hh]);                                           \
                pl_swap(up[2][hh], up[3][hh]);                                           \
            }                                                                            \
            bf16x8 pA0 = __builtin_bit_cast(bf16x8, (u32x4){up[0][0], up[0][1], up[1][0], up[1][1]}); \
            bf16x8 pA1 = __builtin_bit_cast(bf16x8, (u32x4){up[2][0], up[2][1], up[3][0], up[3][1]}); \
            __builtin_amdgcn_s_setprio(1);                                               \
            lacc[qg] = __builtin_amdgcn_mfma_f32_16x16x32_bf16(pA0, ones, lacc[qg], 0, 0, 0); \
            lacc[qg] = __builtin_amdgcn_mfma_f32_16x16x32_bf16(pA1, ones, lacc[qg], 0, 0, 0); \
            _Pragma("unroll")                                                            \
            for (int jt = 0; jt < 4; jt++) {                                             \
                oacc[qg][jt] = __builtin_amdgcn_mfma_f32_16x16x32_bf16(pA0, vf[jt][0], oacc[qg][jt], 0, 0, 0); \
                oacc[qg][jt] = __builtin_amdgcn_mfma_f32_16x16x32_bf16(pA1, vf[jt][1], oacc[qg][jt], 0, 0, 0); \
            }                                                                            \
            __builtin_amdgcn_s_setprio(0);                                               \
        }                                                                                \
        __syncthreads();                                                                 \
    }

    STAGE(0, 0)
    __syncthreads();

    for (int kt = 0; kt < TSEQ / 64; kt += 2) {
        BODY(0, 1, kt, 1)
        BODY(1, 0, kt + 1, (kt + 2 < TSEQ / 64))
    }
    #undef BODY
    #undef STAGE

    // oacc/lacc C-layout: row = q_local = g*4+r, col = l15. lacc columns are all
    // identical (B=ones), so the denominator for row r is lacc[qg][r] in-lane.
    #pragma unroll
    for (int qg = 0; qg < 2; qg++)
        #pragma unroll
        for (int r = 0; r < 4; r++) {
            float inv = 1.f / lacc[qg][r];
            long row = qrow + qg * 16 + g * 4 + r;
            #pragma unroll
            for (int jt = 0; jt < 4; jt++)
                ob[row * 1024 + h * 64 + jt * 16 + l15] = f2bf(oacc[qg][jt][r] * inv);
        }
}

// ---------------------------------------------------------------- launcher
extern "C" void kernel_launch(void* const* d_in, const int* in_sizes, int n_in,
                              void* d_out, int out_size, void* d_ws, size_t ws_size,
                              hipStream_t stream)
{
    const float* x    = (const float*)d_in[0];
    const float* Wqkv = (const float*)d_in[1];
    const float* bqkv = (const float*)d_in[2];
    const float* Wout = (const float*)d_in[3];
    const float* bout = (const float*)d_in[4];
    float* out = (float*)d_out;

    char* ws = (char*)d_ws;
    const size_t SZ_TOKD = (size_t)NTOK * 1024 * sizeof(short);   // 8 MB
    short* xb    = (short*)ws;                 ws += SZ_TOKD;
    short* wqkvt = (short*)ws;                 ws += (size_t)3072 * 1024 * sizeof(short);
    short* woutt = (short*)ws;                 ws += (size_t)1024 * 1024 * sizeof(short);
    short* qb    = (short*)ws;                 ws += SZ_TOKD;
    short* kb    = (short*)ws;                 ws += SZ_TOKD;
    short* vt    = (short*)ws;                 ws += SZ_TOKD;
    short* ob    = (short*)ws;                 ws += SZ_TOKD;
    if ((size_t)(ws - (char*)d_ws) > ws_size) return;   // workspace too small

    prep_kernel<<<8192, 256, 0, stream>>>(x, Wqkv, Wout, xb, wqkvt, woutt);

    gemm_bf16_kernel<0><<<dim3(NTOK / 256, 3072 / 192), 512, 0, stream>>>(
        xb, wqkvt, bqkv, qb, kb, vt, nullptr);

    flash_attn_kernel<<<dim3(TSEQ / 128, BATCH * HEADS), 256, 0, stream>>>(qb, kb, vt, ob);

    gemm_bf16_kernel<1><<<dim3(NTOK / 128, 1024 / 64), 256, 0, stream>>>(
        ob, woutt, bout, nullptr, nullptr, nullptr, out);
}